// Round 11
// baseline (15.629 us; speedup 1.0000x reference)
//
#include <hip/hip_runtime.h>
#include <cmath>

#define NROWS 131072
#define TPB 256

// ---------------------------------------------------------------------------
// Sparse sub-tree (exact f32) + single-latency-round float4 streaming.
// Only 2 layer-1 modules are observable through the one-hot output routing;
// they consume 4 layer-0 modules -> 8 x-columns (grid-uniform).
// R8/R10 both landed at ~14 us: staging ran as 4+ serialized load rounds
// (batch must return before its LDS writes, then next batch issues).
// Here: ALL 16 float4 loads (256B/thread, 64KB/wave) are issued first,
// BEFORE the routing preamble (which hides ~1us of HBM latency), giving one
// latency round + streaming transfer. Deposit: each thread owns 4 fixed
// columns; <=8 exec-masked ds_writes per reg; reads stride-9 conflict-free.
// ---------------------------------------------------------------------------

// top-2 of v across 64 lanes; lowest-index tie-break matches jax.lax.top_k
__device__ __forceinline__ void wave_top2(float v, int lane, int& i1, int& i2) {
    float m1 = v;
#pragma unroll
    for (int off = 32; off; off >>= 1) m1 = fmaxf(m1, __shfl_xor(m1, off));
    unsigned long long bm = __ballot(v == m1);
    i1 = __ffsll(bm) - 1;
    float vx = (lane == i1) ? -INFINITY : v;
    float m2 = vx;
#pragma unroll
    for (int off = 32; off; off >>= 1) m2 = fmaxf(m2, __shfl_xor(m2, off));
    bm = __ballot(vx == m2);
    i2 = __ffsll(bm) - 1;
}

__global__ __launch_bounds__(TPB) void moe_sparse(
    const float* __restrict__ x,
    const float* __restrict__ emb0, const float* __restrict__ emb1,
    const float* __restrict__ emb_out,
    const float* __restrict__ W1_0, const float* __restrict__ b1_0,
    const float* __restrict__ W2_0, const float* __restrict__ b2_0,
    const float* __restrict__ W1_1, const float* __restrict__ b1_1,
    const float* __restrict__ W2_1, const float* __restrict__ b2_1,
    float* __restrict__ out) {

    // rt[0]=io1 rt[1]=io2 rt[2..5]=active layer-0 modules
    // rt[6..13]=ucol[8] (-1 = duplicate, no writer)  rt[14..21]=src[8]
    __shared__ int rt[22];
    __shared__ float buf[256 * 9];   // stride-9 pad -> conflict-free

    const int t = threadIdx.x;

    // ---- 1) issue ALL x loads first: 16 x dwordx4, 256B/thread in flight ----
    // block chunk = 256 rows x 64 f = 4096 float4; stride/step = 256 float4
    const float4* xq = reinterpret_cast<const float4*>(x)
                     + (size_t)blockIdx.x * 4096 + t;
    float4 v[16];
#pragma unroll
    for (int ji = 0; ji < 16; ++ji) v[ji] = xq[(size_t)ji * 256];

    // ---- 2) routing preamble on wave 0 (hides load latency) ----
    if (t < 64) {
        const int lane = t;
        int io1, io2;
        wave_top2(emb_out[lane], lane, io1, io2);
        int a1, b1i, a2, b2i;
        wave_top2(emb1[lane * 64 + io1], lane, a1, b1i);
        wave_top2(emb1[lane * 64 + io2], lane, a2, b2i);
        const int mk[4] = {a1, b1i, a2, b2i};
        int cols[8];
#pragma unroll
        for (int k = 0; k < 4; ++k) {
            int c1, c2;
            wave_top2(emb0[lane * 64 + mk[k]], lane, c1, c2);
            cols[2 * k] = c1; cols[2 * k + 1] = c2;
        }
        int src[8];
#pragma unroll
        for (int s = 0; s < 8; ++s) {
            src[s] = s;
#pragma unroll
            for (int u = 0; u < 8; ++u)
                if (u < s && cols[s] == cols[u] && src[s] == s) src[s] = u;
        }
        if (lane == 0) {
            rt[0] = io1; rt[1] = io2;
            rt[2] = a1; rt[3] = b1i; rt[4] = a2; rt[5] = b2i;
#pragma unroll
            for (int s = 0; s < 8; ++s) {
                rt[6 + s]  = (src[s] == s) ? cols[s] : -1;
                rt[14 + s] = src[s];
            }
        }
    }
    __syncthreads();

    // ---- 3) deposit routed components: 4 fixed columns per thread ----
    const int cbase = (t & 15) * 4;       // this thread's column base
    int s4[4] = {-1, -1, -1, -1};
#pragma unroll
    for (int c = 0; c < 4; ++c)
#pragma unroll
        for (int s = 0; s < 8; ++s)
            if (cbase + c == rt[6 + s]) s4[c] = s;

    const int rsub = t >> 4;              // row-within-16-row-chunk
#pragma unroll
    for (int ji = 0; ji < 16; ++ji) {
        const int row = ji * 16 + rsub;
        if (s4[0] >= 0) buf[row * 9 + s4[0]] = v[ji].x;
        if (s4[1] >= 0) buf[row * 9 + s4[1]] = v[ji].y;
        if (s4[2] >= 0) buf[row * 9 + s4[2]] = v[ji].z;
        if (s4[3] >= 0) buf[row * 9 + s4[3]] = v[ji].w;
    }
    __syncthreads();

    // ---- 4) per-row sparse MLP (exact f32, scalar weights) ----
    const int io1 = __builtin_amdgcn_readfirstlane(rt[0]);
    const int io2 = __builtin_amdgcn_readfirstlane(rt[1]);
    int m[4], srcs[8];
#pragma unroll
    for (int k = 0; k < 4; ++k)
        m[k] = __builtin_amdgcn_readfirstlane(rt[2 + k]);
#pragma unroll
    for (int s = 0; s < 8; ++s)
        srcs[s] = __builtin_amdgcn_readfirstlane(rt[14 + s]);

    float f[8];
#pragma unroll
    for (int s = 0; s < 8; ++s) f[s] = buf[t * 9 + srcs[s]];

    float y[4];
#pragma unroll
    for (int k = 0; k < 4; ++k) {
        const float* w1 = W1_0 + m[k] * 24;
        const float* bb = b1_0 + m[k] * 12;
        const float* w2 = W2_0 + m[k] * 12;
        const float va = f[2 * k], vb = f[2 * k + 1];
        float acc = b2_0[m[k]];
#pragma unroll
        for (int j = 0; j < 12; ++j) {
            float h = fmaf(va, w1[j], fmaf(vb, w1[12 + j], bb[j]));
            acc = fmaf(fmaxf(h, 0.0f), w2[j], acc);
        }
        y[k] = acc;
    }

    float z[2];
    const int mo[2] = {io1, io2};
#pragma unroll
    for (int k = 0; k < 2; ++k) {
        const float* w1 = W1_1 + mo[k] * 24;
        const float* bb = b1_1 + mo[k] * 12;
        const float* w2 = W2_1 + mo[k] * 12;
        const float g1 = k ? y[2] : y[0];
        const float g2 = k ? y[3] : y[1];
        float acc = b2_1[mo[k]];
#pragma unroll
        for (int j = 0; j < 12; ++j) {
            float h = fmaf(g1, w1[j], fmaf(g2, w1[12 + j], bb[j]));
            acc = fmaf(fmaxf(h, 0.0f), w2[j], acc);
        }
        z[k] = acc;
    }

    float2 res;
    res.x = 1.0f / (1.0f + __expf(-z[0]));
    res.y = 1.0f / (1.0f + __expf(-z[1]));
    reinterpret_cast<float2*>(out)[(size_t)blockIdx.x * 256 + t] = res;
}

extern "C" void kernel_launch(void* const* d_in, const int* in_sizes, int n_in,
                              void* d_out, int out_size, void* d_ws, size_t ws_size,
                              hipStream_t stream) {
    const float* x       = (const float*)d_in[0];
    // d_in[1] = task_id; NUM_TASKS == 1 so always 0.
    const float* emb0    = (const float*)d_in[2];
    const float* emb1    = (const float*)d_in[3];
    const float* emb_out = (const float*)d_in[4];
    const float* W1_0    = (const float*)d_in[5];
    const float* b1_0    = (const float*)d_in[6];
    const float* W2_0    = (const float*)d_in[7];
    const float* b2_0    = (const float*)d_in[8];
    const float* W1_1    = (const float*)d_in[9];
    const float* b1_1    = (const float*)d_in[10];
    const float* W2_1    = (const float*)d_in[11];
    const float* b2_1    = (const float*)d_in[12];

    moe_sparse<<<NROWS / TPB, TPB, 0, stream>>>(
        x, emb0, emb1, emb_out,
        W1_0, b1_0, W2_0, b2_0, W1_1, b1_1, W2_1, b2_1,
        (float*)d_out);
}

// Round 12
// 13.279 us; speedup vs baseline: 1.1769x; 1.1769x over previous
//
#include <hip/hip_runtime.h>
#include <cmath>

#define NROWS 131072
#define TPB 256

// ---------------------------------------------------------------------------
// Sparse sub-tree evaluation, exact f32 (R8 structure), barrier-free (R12).
// Only 2 layer-1 modules are observable through the one-hot output routing;
// they consume 4 layer-0 modules -> 8 x-columns. All routing indices are
// grid-uniform and data-independent of x. EVERY wave computes the routing
// redundantly (same wall time as one wave -- it's parallel), which removes
// the __syncthreads + LDS round-trip and makes all waves independent.
// Per thread: 8 gathered features -> 6 tiny f32 MLPs with scalar weights.
// R8/R10/R11 all land 14.0-15.6us vs ~5us of work: launch/replay overhead
// floor; this is the last structural trim.
// ---------------------------------------------------------------------------

// top-2 of v across 64 lanes; lowest-index tie-break matches jax.lax.top_k
__device__ __forceinline__ void wave_top2(float v, int lane, int& i1, int& i2) {
    float m1 = v;
#pragma unroll
    for (int off = 32; off; off >>= 1) m1 = fmaxf(m1, __shfl_xor(m1, off));
    unsigned long long bm = __ballot(v == m1);
    i1 = __ffsll((long long)bm) - 1;
    float vx = (lane == i1) ? -INFINITY : v;
    float m2 = vx;
#pragma unroll
    for (int off = 32; off; off >>= 1) m2 = fmaxf(m2, __shfl_xor(m2, off));
    bm = __ballot(vx == m2);
    i2 = __ffsll((long long)bm) - 1;
}

__device__ __forceinline__ int rfl(int v) {
    return __builtin_amdgcn_readfirstlane(v);
}

__global__ __launch_bounds__(TPB) void moe_sparse(
    const float* __restrict__ x,
    const float* __restrict__ emb0, const float* __restrict__ emb1,
    const float* __restrict__ emb_out,
    const float* __restrict__ W1_0, const float* __restrict__ b1_0,
    const float* __restrict__ W2_0, const float* __restrict__ b2_0,
    const float* __restrict__ W1_1, const float* __restrict__ b1_1,
    const float* __restrict__ W2_1, const float* __restrict__ b2_1,
    float* __restrict__ out) {

    const int lane = threadIdx.x & 63;

    // ---- routing: computed by every wave (no barrier, no LDS) ----
    int io1, io2;
    wave_top2(emb_out[lane], lane, io1, io2);
    io1 = rfl(io1); io2 = rfl(io2);

    int m[4];
    {
        int a1, b1i, a2, b2i;
        wave_top2(emb1[lane * 64 + io1], lane, a1, b1i);
        wave_top2(emb1[lane * 64 + io2], lane, a2, b2i);
        m[0] = rfl(a1); m[1] = rfl(b1i); m[2] = rfl(a2); m[3] = rfl(b2i);
    }

    int ca[4], cb[4];
#pragma unroll
    for (int k = 0; k < 4; ++k) {
        int c1, c2;
        wave_top2(emb0[lane * 64 + m[k]], lane, c1, c2);
        ca[k] = rfl(c1); cb[k] = rfl(c2);
    }

    // ---- gather this row's 8 routed features (8 loads in flight) ----
    const int row = blockIdx.x * TPB + threadIdx.x;
    const float* xr = x + (size_t)row * 64;
    float va[4], vb[4];
#pragma unroll
    for (int k = 0; k < 4; ++k) { va[k] = xr[ca[k]]; vb[k] = xr[cb[k]]; }

    // ---- layer 0: the 4 active modules, f32, scalar (SGPR) weights ----
    float y[4];
#pragma unroll
    for (int k = 0; k < 4; ++k) {
        const float* w1 = W1_0 + m[k] * 24;
        const float* bb = b1_0 + m[k] * 12;
        const float* w2 = W2_0 + m[k] * 12;
        float acc = b2_0[m[k]];
#pragma unroll
        for (int j = 0; j < 12; ++j) {
            float h = fmaf(va[k], w1[j], fmaf(vb[k], w1[12 + j], bb[j]));
            acc = fmaf(fmaxf(h, 0.0f), w2[j], acc);
        }
        y[k] = acc;
    }

    // ---- layer 1: io1 consumes (y[0],y[1]); io2 consumes (y[2],y[3]) ----
    float z[2];
    const int mo[2] = {io1, io2};
#pragma unroll
    for (int k = 0; k < 2; ++k) {
        const float* w1 = W1_1 + mo[k] * 24;
        const float* bb = b1_1 + mo[k] * 12;
        const float* w2 = W2_1 + mo[k] * 12;
        const float g1 = k ? y[2] : y[0];
        const float g2 = k ? y[3] : y[1];
        float acc = b2_1[mo[k]];
#pragma unroll
        for (int j = 0; j < 12; ++j) {
            float h = fmaf(g1, w1[j], fmaf(g2, w1[12 + j], bb[j]));
            acc = fmaf(fmaxf(h, 0.0f), w2[j], acc);
        }
        z[k] = acc;
    }

    float2 res;
    res.x = 1.0f / (1.0f + __expf(-z[0]));
    res.y = 1.0f / (1.0f + __expf(-z[1]));
    reinterpret_cast<float2*>(out)[row] = res;
}

extern "C" void kernel_launch(void* const* d_in, const int* in_sizes, int n_in,
                              void* d_out, int out_size, void* d_ws, size_t ws_size,
                              hipStream_t stream) {
    const float* x       = (const float*)d_in[0];
    // d_in[1] = task_id; NUM_TASKS == 1 so always 0.
    const float* emb0    = (const float*)d_in[2];
    const float* emb1    = (const float*)d_in[3];
    const float* emb_out = (const float*)d_in[4];
    const float* W1_0    = (const float*)d_in[5];
    const float* b1_0    = (const float*)d_in[6];
    const float* W2_0    = (const float*)d_in[7];
    const float* b2_0    = (const float*)d_in[8];
    const float* W1_1    = (const float*)d_in[9];
    const float* b1_1    = (const float*)d_in[10];
    const float* W2_1    = (const float*)d_in[11];
    const float* b2_1    = (const float*)d_in[12];

    moe_sparse<<<NROWS / TPB, TPB, 0, stream>>>(
        x, emb0, emb1, emb_out,
        W1_0, b1_0, W2_0, b2_0, W1_1, b1_1, W2_1, b2_1,
        (float*)d_out);
}